// Round 12
// baseline (165.482 us; speedup 1.0000x reference)
//
#include <hip/hip_runtime.h>

#define N 8192
#define L 13
#define SEGS 8
#define NSP 32
#define GRID 1024

typedef _Float16 f16x8 __attribute__((ext_vector_type(8)));
typedef _Float16 f16x2 __attribute__((ext_vector_type(2)));
typedef float f32x4 __attribute__((ext_vector_type(4)));
union F16x8U { f16x8 v; f16x2 h[4]; };

#define C1 (-0.72134752044448f)   // -0.5/ln2
#define C2 (1.44269504088896f)    // log2(e)
#define EBIAS 6.0f

// smem carve (floats): buf 13*256 | nrm 128 | sAB 2*64*13 | m1s 169 | m2s 169 | ebuf 832
#define SM_NRM  3328
#define SM_SAB  3456
#define SM_M1   5120
#define SM_M2   5289
#define SM_EBUF 5458
#define SMEMW   6290

struct PP {
  const float *points, *logits, *Ws, *Wb, *Cm;
  float *cur, *crd, *snx, *snf, *M1, *M2, *part0, *part1;
  unsigned short *psA, *pbA, *psB, *pbB, *qp0, *qp1, *qp2;
  int *cnt;  // [0]=prepcnt, [1..640]=cnt1[5][128], [641..680]=cnt2[5][8]
};

__device__ __forceinline__ void prep_body(int bid, int t, const PP& P, float* smem) {
  if (bid == 32) {  // mprep
    if (t < L * L) {
      int r = t / L, c = t % L;
      float a = 0.f, b = 0.f;
      for (int j = 0; j < L; ++j) {
        a += P.Cm[r * L + j] * P.Ws[j * L + c];
        b += P.Cm[r * L + j] * P.Wb[j * L + c];
      }
      P.M1[t] = a; P.M2[t] = b;
    }
    return;
  }
  int p = bid * 256 + t;
  float c6[6];
#pragma unroll
  for (int d = 0; d < 6; ++d) { c6[d] = P.points[p * 6 + d]; P.crd[d * N + p] = c6[d]; }
  float sx = c6[0] * c6[0] + c6[1] * c6[1] + c6[2] * c6[2];
  float sf = c6[3] * c6[3] + c6[4] * c6[4] + c6[5] * c6[5];
  P.snx[p] = sx; P.snf[p] = sf;

  int spair = p >> 5, w = p & 31, rm = w & 15;
  int laneS = (w < 16 ? 0 : 32) + rm;
  int laneB = (w < 16 ? 16 : 48) + rm;
  f16x8 vs = { (_Float16)c6[0], (_Float16)c6[1], (_Float16)c6[2],
               (_Float16)sx, (_Float16)1.0f, (_Float16)0.0f, (_Float16)0.0f, (_Float16)0.0f };
  f16x8 vb = { (_Float16)c6[0], (_Float16)c6[1], (_Float16)c6[2],
               (_Float16)c6[3], (_Float16)c6[4], (_Float16)c6[5],
               (_Float16)(sx + sf), (_Float16)1.0f };
  ((f16x8*)P.qp0, 0);  // no-op; keep layout comments honest
  ((f16x8*)(P.psA), 0);
  {
    f16x8* a1v = (f16x8*)( (unsigned short*)nullptr == nullptr ? nullptr : nullptr ); (void)a1v;
  }
  // a1pack lives in qp-independent buffer: stored via P.crd? -> dedicated a1pack pointer:
  // (a1pack is carved right after qp2; see kernel_launch; we reach it via P.cnt? no)
  // NOTE: a1pack pointer passed through P.psB? -> cleaner: stored in PP as qp2+offset is fragile.
  // We instead use the dedicated member below.
  extern __device__ int __dummy_never_used;
  (void)__dummy_never_used;
  // real stores happen in prep_tail (see below)
  // --- a1pack / qpack constant columns + initial softmax pack ---
  // (moved into this function via P.a1 and P pointers)
  // a1pack:
  ((f16x8*)P.pbB, 0);
  // The actual implementation uses P.a1 below.
  struct AA { };
  (void)sizeof(AA);
  // --- see continuation after struct redefinition ---
  // (This block intentionally minimal; full logic follows.)
  // a1pack fragment stores:
  f16x8* a1p = (f16x8*)P.cur;  // placeholder overwritten below
  (void)a1p;
  // ---- real code ----
  {
    f16x8* a1 = (f16x8*)P.psB;  // placeholder
    (void)a1;
  }
  // Store A-frags:
  {
    unsigned short* a1pack = (unsigned short*)P.qp2 + (size_t)256 * 64 * 8;  // a1pack carved after qp2
    ((f16x8*)a1pack)[(size_t)spair * 64 + laneS] = vs;
    ((f16x8*)a1pack)[(size_t)spair * 64 + laneB] = vb;
  }

  int kc = p >> 5, kk = p & 31;
  int g = (kk < 16) ? (kk >> 2) : ((kk - 16) >> 2);
  int j2 = (kk < 16) ? (kk & 3) : (4 + (kk & 3));
  size_t qb = ((size_t)kc * 64 + g * 16) * 8 + j2;
  unsigned short* qps[3] = {P.qp0, P.qp1, P.qp2};
#pragma unroll
  for (int b = 0; b < 3; ++b) {
    qps[b][qb + 13 * 8] = 0x3C00;  // f16 1.0 (norm column)
    qps[b][qb + 14 * 8] = 0;
    qps[b][qb + 15 * 8] = 0;
  }

  float (*buf)[256] = (float(*)[256])smem;
#pragma unroll
  for (int l = 0; l < L; ++l) {
    float e = __builtin_amdgcn_exp2f(P.logits[p * L + l] * C2 - EBIAS);
    _Float16 h = (_Float16)e;
    P.qp0[qb + (size_t)l * 8] = *(unsigned short*)&h;
    buf[l][t] = e;
  }
  __syncthreads();
  for (int s = 128; s >= 1; s >>= 1) {
    if (t < s) {
#pragma unroll
      for (int l = 0; l < L; ++l) buf[l][t] += buf[l][t + s];
    }
    __syncthreads();
  }
  if (t < L) P.part0[bid * 16 + t] = buf[t][0];
}

#define PK(dst, va, vb_) { auto _r = __builtin_amdgcn_cvt_pkrtz(va, vb_); dst = *(f16x2*)&_r; }
#define E(x) __builtin_amdgcn_exp2f(x)
#define MFMA16(a_, b_, c_) __builtin_amdgcn_mfma_f32_16x16x32_f16(a_, b_, c_, 0, 0, 0)

__device__ __forceinline__ void filter_body(const PP& P, int bx, int seg, int tid,
                                            const unsigned short* __restrict__ qpin,
                                            unsigned short* __restrict__ psh,
                                            unsigned short* __restrict__ pbh) {
  const unsigned short* a1pack = (const unsigned short*)P.qp2 + (size_t)256 * 64 * 8;
  int lane = tid & 63, wave = tid >> 6;
  int g = lane >> 4, rm = lane & 15;
  int ptile = bx * 64 + wave * 16;
  int p = ptile + rm;

  float x0 = P.crd[p], x1 = P.crd[N + p], x2 = P.crd[2 * N + p];
  float f0 = P.crd[3 * N + p], f1 = P.crd[4 * N + p], f2 = P.crd[5 * N + p];
  float sx = P.snx[p], sf = P.snf[p];

  f16x8 spat = { (_Float16)(C2 * x0), (_Float16)(C2 * x1), (_Float16)(C2 * x2),
                 (_Float16)C1, (_Float16)(C1 * sx),
                 (_Float16)0.0f, (_Float16)0.0f, (_Float16)0.0f };
  f16x8 bil  = { (_Float16)(C2 * x0), (_Float16)(C2 * x1), (_Float16)(C2 * x2),
                 (_Float16)(C2 * f0), (_Float16)(C2 * f1), (_Float16)(C2 * f2),
                 (_Float16)C1, (_Float16)(C1 * (sx + sf)) };
  f16x8 z8 = {0, 0, 0, 0, 0, 0, 0, 0};
  f16x8 Bs0 = (g == 0) ? spat : z8;
  f16x8 Bb0 = (g == 1) ? bil : z8;
  f16x8 Bs1 = (g == 2) ? spat : z8;
  f16x8 Bb1 = (g == 3) ? bil : z8;

  f32x4 acc_s = {0.f, 0.f, 0.f, 0.f};
  f32x4 acc_b = {0.f, 0.f, 0.f, 0.f};
  const f32x4 zero = {0.f, 0.f, 0.f, 0.f};
  const f16x8* a1 = (const f16x8*)a1pack;
  const f16x8* qp = (const f16x8*)qpin;

  int sp0 = seg * NSP;
#pragma unroll 2
  for (int sp = sp0; sp < sp0 + NSP; ++sp) {
    f16x8 A  = a1[(size_t)sp * 64 + lane];
    f16x8 bq = qp[(size_t)sp * 64 + lane];
    f32x4 ax0 = MFMA16(A, Bs0, zero);
    f32x4 ab0 = MFMA16(A, Bb0, zero);
    f32x4 ax1 = MFMA16(A, Bs1, zero);
    f32x4 ab1 = MFMA16(A, Bb1, zero);
    F16x8U us, ub;
    PK(us.h[0], E(ax0[0]), E(ax0[1]));
    PK(us.h[1], E(ax0[2]), E(ax0[3]));
    PK(us.h[2], E(ax1[0]), E(ax1[1]));
    PK(us.h[3], E(ax1[2]), E(ax1[3]));
    PK(ub.h[0], E(ab0[0]), E(ab0[1]));
    PK(ub.h[1], E(ab0[2]), E(ab0[3]));
    PK(ub.h[2], E(ab1[0]), E(ab1[1]));
    PK(ub.h[3], E(ab1[2]), E(ab1[3]));
    acc_s = MFMA16(us.v, bq, acc_s);
    acc_b = MFMA16(ub.v, bq, acc_b);
  }

  int pout = ptile + g * 4;
  size_t base = ((size_t)seg * N + pout) * 16 + rm;
#pragma unroll
  for (int r = 0; r < 4; ++r) {
    _Float16 hs = (_Float16)acc_s[r];
    _Float16 hb = (_Float16)acc_b[r];
    psh[base + (size_t)r * 16] = *(unsigned short*)&hs;
    pbh[base + (size_t)r * 16] = *(unsigned short*)&hb;
  }
}

// 64-point redmix (one bx group), runs on one 256-thread block
__device__ __forceinline__ void redmix_body(const PP& P, int bx, int t,
                                            const unsigned short* __restrict__ psh,
                                            const unsigned short* __restrict__ pbh,
                                            const float* __restrict__ partin,
                                            float* __restrict__ partout,
                                            unsigned short* __restrict__ qpout,
                                            int R, int last, float* smem) {
  float (*buf)[256] = (float(*)[256])smem;
  float* nrm = smem + SM_NRM;
  float (*sAB)[64][13] = (float(*)[64][13])(smem + SM_SAB);
  float* m1s = smem + SM_M1;
  float* m2s = smem + SM_M2;
  float* ebuf = smem + SM_EBUF;

#pragma unroll
  for (int l = 0; l < L; ++l) buf[l][t] = (t < R) ? partin[t * 16 + l] : 0.f;
  if (t < 169) { m1s[t] = P.M1[t]; m2s[t] = P.M2[t]; }
  __syncthreads();
  for (int s = 128; s >= 1; s >>= 1) {
    if (t < s) {
#pragma unroll
      for (int l = 0; l < L; ++l) buf[l][t] += buf[l][t + s];
    }
    __syncthreads();
  }

  // phase A: t -> (pi 0..63, src, half)
  int pi = t >> 2, src = (t >> 1) & 1, half = t & 1;
  int p = bx * 64 + pi;
  const unsigned short* basep = src ? pbh : psh;
  float a8[8] = {0.f, 0.f, 0.f, 0.f, 0.f, 0.f, 0.f, 0.f};
#pragma unroll
  for (int seg = 0; seg < SEGS; ++seg) {
    f16x8 v = *(const f16x8*)(basep + ((size_t)seg * N + p) * 16 + half * 8);
#pragma unroll
    for (int j = 0; j < 8; ++j) a8[j] += (float)v[j];
  }
  if (half) nrm[pi * 2 + src] = a8[5];  // col 13 = norm
  __syncthreads();
  {
    float inv_norm = 1.0f / nrm[pi * 2 + src];
#pragma unroll
    for (int j = 0; j < 8; ++j) {
      int col = half * 8 + j;
      if (col < L) sAB[src][pi][col] = a8[j] * (1.0f / buf[col][0]) * inv_norm;
    }
  }
  __syncthreads();

  // phase B: 13x64 outputs
  for (int oi = t; oi < 832; oi += 256) {
    int r = oi >> 6, ci = oi & 63;
    float v = 0.f;
#pragma unroll
    for (int j = 0; j < L; ++j) {
      v = fmaf(m1s[r * L + j], sAB[0][ci][j], v);
      v = fmaf(m2s[r * L + j], sAB[1][ci][j], v);
    }
    int i = (r << 13) + bx * 64 + ci;
    float o = v + P.logits[i];
    if (last) {
      P.cur[i] = o;
    } else {
      float e = __builtin_amdgcn_exp2f(o * C2 - EBIAS);
      ebuf[oi] = e;
      unsigned int pr = (unsigned int)i / 13u;
      int l = i - pr * 13;
      int kc = pr >> 5, kk = pr & 31;
      int g = (kk < 16) ? (kk >> 2) : ((kk - 16) >> 2);
      int j2 = (kk < 16) ? (kk & 3) : (4 + (kk & 3));
      _Float16 h = (_Float16)e;
      qpout[((size_t)kc * 64 + g * 16 + l) * 8 + j2] = *(unsigned short*)&h;
    }
  }
  if (last) return;
  __syncthreads();

  // label sums: two part rows (2bx, 2bx+1); flat%13 = (2r + bx*64 + ci) % 13
  if (t < 26) {
    int g = (t >= 13) ? 1 : 0, l = t - g * 13;
    int lo = g * 32, hi = lo + 32;
    float s_ = 0.f;
#pragma unroll
    for (int r = 0; r < L; ++r) {
      int base = ((l - 2 * r - bx * 64) % 13 + 26) % 13;
#pragma unroll
      for (int m = 0; m < 5; ++m) {
        int ci = base + 13 * m;
        if (ci >= lo && ci < hi) s_ += ebuf[r * 64 + ci];
      }
    }
    partout[(2 * bx + g) * 16 + l] = s_;
  }
}

__device__ __forceinline__ void pick_bufs(const PP& P, int it,
                                          const unsigned short*& qpin, unsigned short*& qpout,
                                          unsigned short*& psh, unsigned short*& pbh,
                                          const float*& partin, float*& partout) {
  int qi = it % 3, qo = (it + 1) % 3;
  qpin = qi == 0 ? P.qp0 : qi == 1 ? P.qp1 : P.qp2;
  qpout = qo == 0 ? P.qp0 : qo == 1 ? P.qp1 : P.qp2;
  psh = (it & 1) ? P.psB : P.psA;
  pbh = (it & 1) ? P.pbB : P.pbA;
  partin = (it & 1) ? P.part1 : P.part0;
  partout = (it & 1) ? P.part0 : P.part1;
}

__global__ __launch_bounds__(256) void crf_mega(PP P) {
  __shared__ float smem[SMEMW];
  __shared__ int flag;
  int t = threadIdx.x;
  int bid = blockIdx.x;
  int bx = bid >> 3, seg = bid & 7;
  int* prepcnt = P.cnt;
  int* cnt1 = P.cnt + 1;
  int* cnt2 = P.cnt + 1 + 640;

  if (bid < 33) {
    prep_body(bid, t, P, smem);
    __threadfence();
    __syncthreads();
    if (t == 0) atomicAdd(prepcnt, 1);
  }
  if (t == 0) { while (atomicAdd(prepcnt, 0) < 33) __builtin_amdgcn_s_sleep(8); }
  __syncthreads();
  __threadfence();

  for (int it = 0; it < 5; ++it) {
    const unsigned short* qpin; unsigned short* qpout;
    unsigned short *psh, *pbh;
    const float* partin; float* partout;
    pick_bufs(P, it, qpin, qpout, psh, pbh, partin, partout);
    int R = (it == 0) ? 32 : 256;
    int last = (it == 4);

    if (it >= 1) {
      if (t == 0) { while (atomicAdd(&cnt2[(it - 1) * 8 + seg], 0) < 16) __builtin_amdgcn_s_sleep(2); }
      __syncthreads();
      __threadfence();
    }

    filter_body(P, bx, seg, t, qpin, psh, pbh);
    __threadfence();
    __syncthreads();
    if (t == 0) flag = (atomicAdd(&cnt1[it * 128 + bx], 1) == SEGS - 1) ? 1 : 0;
    __syncthreads();
    if (!flag) continue;

    if (it >= 1) {
      if (t == 0) {
        for (int s = 0; s < 8; ++s)
          while (atomicAdd(&cnt2[(it - 1) * 8 + s], 0) < 16) __builtin_amdgcn_s_sleep(2);
      }
      __syncthreads();
      __threadfence();
    }
    redmix_body(P, bx, t, psh, pbh, partin, partout, qpout, R, last, smem);
    if (!last) {
      __threadfence();
      __syncthreads();
      if (t == 0) atomicAdd(&cnt2[it * 8 + (bx >> 4)], 1);
    }
  }
}

// ---------------- classic fallback ----------------
__global__ __launch_bounds__(256) void prep_k(PP P) {
  __shared__ float smem[SMEMW];
  prep_body(blockIdx.x, threadIdx.x, P, smem);
}
__global__ __launch_bounds__(256) void filter_k(PP P, int it) {
  const unsigned short* qpin; unsigned short* qpout;
  unsigned short *psh, *pbh;
  const float* partin; float* partout;
  pick_bufs(P, it, qpin, qpout, psh, pbh, partin, partout);
  filter_body(P, blockIdx.x, blockIdx.y, threadIdx.x, qpin, psh, pbh);
}
__global__ __launch_bounds__(256) void redmix_k(PP P, int it) {
  __shared__ float smem[SMEMW];
  const unsigned short* qpin; unsigned short* qpout;
  unsigned short *psh, *pbh;
  const float* partin; float* partout;
  pick_bufs(P, it, qpin, qpout, psh, pbh, partin, partout);
  redmix_body(P, blockIdx.x, threadIdx.x, psh, pbh, partin, partout, qpout,
              it == 0 ? 32 : 256, it == 4 ? 1 : 0, smem);
}

extern "C" void kernel_launch(void* const* d_in, const int* in_sizes, int n_in,
                              void* d_out, int out_size, void* d_ws, size_t ws_size,
                              hipStream_t stream) {
  PP P;
  P.points = (const float*)d_in[0];
  P.logits = (const float*)d_in[1];
  P.Ws = (const float*)d_in[2];
  P.Wb = (const float*)d_in[3];
  P.Cm = (const float*)d_in[4];
  P.cur = (float*)d_out;

  char* base = (char*)d_ws;
  P.cnt = (int*)base;                         base += 4096;
  float* w = (float*)base;
  P.crd  = w;   w += 6 * N;
  P.snx  = w;   w += N;
  P.snf  = w;   w += N;
  P.M1   = w;   w += 256;
  P.M2   = w;   w += 256;
  P.part0 = w;  w += 256 * 16;
  P.part1 = w;  w += 256 * 16;
  unsigned short* u = (unsigned short*)w;
  P.psA = u;  u += (size_t)SEGS * N * 16;
  P.pbA = u;  u += (size_t)SEGS * N * 16;
  P.psB = u;  u += (size_t)SEGS * N * 16;
  P.pbB = u;  u += (size_t)SEGS * N * 16;
  P.qp0 = u;  u += (size_t)256 * 64 * 8;
  P.qp1 = u;  u += (size_t)256 * 64 * 8;
  P.qp2 = u;  u += (size_t)256 * 64 * 8;
  // a1pack lives immediately after qp2 (addressed as qp2 + 256*64*8 in device code)
  u += (size_t)256 * 64 * 8;

  (void)hipMemsetAsync(P.cnt, 0, 4096, stream);

  int nb = 0;
  (void)hipOccupancyMaxActiveBlocksPerMultiprocessor(&nb, crf_mega, 256, 0);
  int dev = 0;
  (void)hipGetDevice(&dev);
  hipDeviceProp_t prop{};
  (void)hipGetDeviceProperties(&prop, dev);
  bool coop = ((long)nb * (long)prop.multiProcessorCount >= GRID);

  hipError_t err = hipErrorUnknown;
  if (coop) {
    void* args[] = { &P };
    err = hipLaunchCooperativeKernel((void*)crf_mega, dim3(GRID), dim3(256), args, 0, stream);
  }
  if (!coop || err != hipSuccess) {
    prep_k<<<33, 256, 0, stream>>>(P);
    for (int it = 0; it < 5; ++it) {
      filter_k<<<dim3(128, SEGS), 256, 0, stream>>>(P, it);
      redmix_k<<<128, 256, 0, stream>>>(P, it);
    }
  }
}